// Round 1
// baseline (560.842 us; speedup 1.0000x reference)
//
#include <hip/hip_runtime.h>
#include <math.h>

// Problem constants: N=256, C=4, F=256, NB=32, OC*OF=1024, K=2048
namespace {
constexpr int N_ = 256, C_ = 4, F_ = 256, NB_ = 32;
constexpr int O_ = 1024;
constexpr int OUT_ELEMS = N_ * O_;  // out (256,1024), then adj follows
typedef float f32x4 __attribute__((ext_vector_type(4)));  // native vec for nontemporal
}

// One block per (n,c). Algebra: fadj[a,b] = x[a]*s[b] + x[b]*s[a] (rank-1 sym,
// s = neighbor-sum), t = signsqrt(fadj), adj[a,b] = t[a,b]*inv[b],
// inv[b] = 1/(colsum_a |t[a,b]| + 1e-7), ax[b] = sum_a t[a,b]*(inv[a]*x[a]).
// KEY identity: sign(v)*sqrt(clip(|v|,1e-8)) == v * rsq(max(|v|,1e-8))
//   - exact for v==0 (0*rsq = 0 == sign(0)*sqrt)
//   - |v|<1e-8 differs by <=1e-4 in t -> ~1e-6 in adj (measure-zero cases)
// One v_rsq_f32 replaces sqrt+cmp+cndmask+copysign; phase-1 |t| folds into
// v_fmac with free abs modifier. {x,s,w} packed in one LDS float4 so the
// per-row broadcast is a single ds_read.
__global__ __launch_bounds__(256) void adj_kernel(
    const float* __restrict__ x,         // (N,C,F)
    const float* __restrict__ neighbor,  // (N,NB,C,F)
    float* __restrict__ adj,             // (N,C,F,F)
    float* __restrict__ ax_out)          // (N,C,F) workspace
{
  __shared__ float4 xsw[F_];   // {x, s, w=inv*x, 0}
  __shared__ float red[4][F_];
  const int blk = blockIdx.x;
  const int n = blk >> 2, c = blk & 3;
  const int t = threadIdx.x;
  const int rs = t >> 6;         // row slice (wave id), rows [rs*64, rs*64+64)
  const int lane = t & 63;
  const int b0 = lane * 4;       // 4 owned columns

  // Stage x row and neighbor-sum row (coalesced).
  const int base = (n * C_ + c) * F_;
  {
    const float xv = x[base + t];
    const float* p = neighbor + ((size_t)(n * NB_) * C_ + c) * F_ + t;
    float s = 0.f;
    #pragma unroll
    for (int j = 0; j < NB_; ++j) s += p[(size_t)j * C_ * F_];
    xsw[t] = make_float4(xv, s, 0.f, 0.f);
  }
  __syncthreads();

  float xbv[4], sbv[4];
  #pragma unroll
  for (int j = 0; j < 4; ++j) {
    const float4 q = xsw[b0 + j];
    xbv[j] = q.x;
    sbv[j] = q.y;
  }

  // Phase 1: partial column sums of |t| over this thread's 64 rows.
  float cs[4] = {0.f, 0.f, 0.f, 0.f};
  const int a0r = rs * 64;
  #pragma unroll 4
  for (int a = a0r; a < a0r + 64; ++a) {
    const float2 xs = *(const float2*)&xsw[a];   // b64 broadcast
    const float xa = xs.x, sa = xs.y;
    #pragma unroll
    for (int j = 0; j < 4; ++j) {
      float v = fmaf(xa, sbv[j], xbv[j] * sa);
      float m = fmaxf(fabsf(v), 1e-8f);
      float rq = __builtin_amdgcn_rsqf(m);
      cs[j] = fmaf(fabsf(v), rq, cs[j]);         // |t| = |v|*rsq
    }
  }
  *(float4*)&red[rs][b0] = make_float4(cs[0], cs[1], cs[2], cs[3]);
  __syncthreads();

  float invv[4];
  {
    const float4 r0 = *(const float4*)&red[0][b0];
    const float4 r1 = *(const float4*)&red[1][b0];
    const float4 r2 = *(const float4*)&red[2][b0];
    const float4 r3 = *(const float4*)&red[3][b0];
    invv[0] = 1.f / (r0.x + r1.x + r2.x + r3.x + 1e-7f);
    invv[1] = 1.f / (r0.y + r1.y + r2.y + r3.y + 1e-7f);
    invv[2] = 1.f / (r0.z + r1.z + r2.z + r3.z + 1e-7f);
    invv[3] = 1.f / (r0.w + r1.w + r2.w + r3.w + 1e-7f);
  }
  if (rs == 0) {
    #pragma unroll
    for (int j = 0; j < 4; ++j) xsw[b0 + j].z = invv[j] * xbv[j];
  }
  __syncthreads();

  // Phase 2: recompute t, float4 nontemporal adj stores, ax accumulation.
  float axp[4] = {0.f, 0.f, 0.f, 0.f};
  float* arow = adj + (size_t)(n * C_ + c) * (F_ * F_);
  #pragma unroll 4
  for (int a = a0r; a < a0r + 64; ++a) {
    const float4 q = xsw[a];                     // single b128 broadcast
    const float xa = q.x, sa = q.y, wa = q.z;
    float o[4];
    #pragma unroll
    for (int j = 0; j < 4; ++j) {
      float v = fmaf(xa, sbv[j], xbv[j] * sa);
      float m = fmaxf(fabsf(v), 1e-8f);
      float rq = __builtin_amdgcn_rsqf(m);
      float tt = v * rq;                         // sign(v)*sqrt(|v|)
      o[j] = tt * invv[j];
      axp[j] = fmaf(tt, wa, axp[j]);
    }
    f32x4 ov = {o[0], o[1], o[2], o[3]};
    __builtin_nontemporal_store(ov, (f32x4*)&arow[(size_t)a * F_ + b0]);
  }
  *(float4*)&red[rs][b0] = make_float4(axp[0], axp[1], axp[2], axp[3]);
  __syncthreads();
  if (rs == 0) {
    const float4 r0 = *(const float4*)&red[0][b0];
    const float4 r1 = *(const float4*)&red[1][b0];
    const float4 r2 = *(const float4*)&red[2][b0];
    const float4 r3 = *(const float4*)&red[3][b0];
    const float4 axv = make_float4(r0.x + r1.x + r2.x + r3.x,
                                   r0.y + r1.y + r2.y + r3.y,
                                   r0.z + r1.z + r2.z + r3.z,
                                   r0.w + r1.w + r2.w + r3.w);
    *(float4*)&ax_out[base + b0] = axv;
  }
}

// out[m][o] = sum_k xcat[m][k] W[o][k], xcat = [ax | x] split at k=1024.
// 128x128 tile, 256 threads, 8x8 register micro-tile (64 fma per 4
// ds_read_b128), BK=32 staged transposed in LDS with skew p(c)=c+4*(c>>5)
// (B-fragment reads become free 2-way instead of 4-way bank conflict).
// split-K=16 -> grid 2x8x16 = 256 blocks = 1/CU; next BK-tile is
// register-prefetched so global latency hides under the fma phase.
// fp32 atomics into pre-zeroed out.
namespace {
constexpr int TM = 128, TO = 128, BK = 32, PL = 144;  // padded/skewed row
__device__ __forceinline__ int swz(int c) { return c + ((c >> 5) << 2); }
}

__global__ __launch_bounds__(256) void gemm_kernel(
    const float* __restrict__ ax,  // (256,1024)
    const float* __restrict__ x,   // (256,1024)
    const float* __restrict__ W,   // (1024,2048)
    float* __restrict__ out)       // (256,1024)
{
  __shared__ float As[BK * PL];  // [kk][m'] skewed
  __shared__ float Bs[BK * PL];  // [kk][o'] skewed
  const int tid = threadIdx.x;
  const int m0 = blockIdx.x * TM, o0 = blockIdx.y * TO;
  const int kbeg = blockIdx.z * 128;  // 128-aligned chunks never straddle halves
  const float* Ab = (kbeg < 1024) ? ax + kbeg : x + (kbeg - 1024);

  // staging coords: 2 threads per row, 16 k's each
  const int sr = tid >> 1;             // tile row (0..127)
  const int kq = (tid & 1) * 16;       // k offset within BK
  const int psr = swz(sr);
  // compute coords: 8x8 micro-tile
  const int mi = tid >> 4, oi = tid & 15;
  const int pa = swz(mi * 8), pb = swz(oi * 8);

  const float* Arow = Ab + (size_t)(m0 + sr) * 1024 + kq;
  const float* Brow = W + (size_t)(o0 + sr) * 2048 + kbeg + kq;

  float4 ra[4], rb[4];
  #pragma unroll
  for (int q = 0; q < 4; ++q) {
    ra[q] = *(const float4*)&Arow[q * 4];
    rb[q] = *(const float4*)&Brow[q * 4];
  }

  float acc[8][8] = {};

  for (int tt = 0; tt < 4; ++tt) {
    // staged regs -> LDS (transposed, skewed); 2-way bank = free
    #pragma unroll
    for (int q = 0; q < 4; ++q) {
      const float av[4] = {ra[q].x, ra[q].y, ra[q].z, ra[q].w};
      const float bv[4] = {rb[q].x, rb[q].y, rb[q].z, rb[q].w};
      #pragma unroll
      for (int e = 0; e < 4; ++e) {
        As[(kq + q * 4 + e) * PL + psr] = av[e];
        Bs[(kq + q * 4 + e) * PL + psr] = bv[e];
      }
    }
    __syncthreads();
    // register-prefetch next BK-tile; latency hides under 2048 fmas
    if (tt < 3) {
      #pragma unroll
      for (int q = 0; q < 4; ++q) {
        ra[q] = *(const float4*)&Arow[(tt + 1) * BK + q * 4];
        rb[q] = *(const float4*)&Brow[(tt + 1) * BK + q * 4];
      }
    }
    #pragma unroll 8
    for (int kk = 0; kk < BK; ++kk) {
      const float4 a0 = *(const float4*)&As[kk * PL + pa];
      const float4 a1 = *(const float4*)&As[kk * PL + pa + 4];
      const float4 b0 = *(const float4*)&Bs[kk * PL + pb];
      const float4 b1 = *(const float4*)&Bs[kk * PL + pb + 4];
      const float am[8] = {a0.x, a0.y, a0.z, a0.w, a1.x, a1.y, a1.z, a1.w};
      const float bm[8] = {b0.x, b0.y, b0.z, b0.w, b1.x, b1.y, b1.z, b1.w};
      #pragma unroll
      for (int i = 0; i < 8; ++i)
        #pragma unroll
        for (int j = 0; j < 8; ++j)
          acc[i][j] = fmaf(am[i], bm[j], acc[i][j]);
    }
    __syncthreads();  // reads done before next overwrite
  }

  #pragma unroll
  for (int i = 0; i < 8; ++i) {
    float* orow = &out[(size_t)(m0 + mi * 8 + i) * 1024 + o0 + oi * 8];
    #pragma unroll
    for (int j = 0; j < 8; ++j) atomicAdd(&orow[j], acc[i][j]);
  }
}

extern "C" void kernel_launch(void* const* d_in, const int* in_sizes, int n_in,
                              void* d_out, int out_size, void* d_ws,
                              size_t ws_size, hipStream_t stream) {
  const float* x = (const float*)d_in[0];         // (256,4,256)
  const float* neighbor = (const float*)d_in[1];  // (256,32,4,256)
  const float* W = (const float*)d_in[2];         // (1024,2048)
  float* out = (float*)d_out;                     // output 0: (256,1024)
  float* adj = out + OUT_ELEMS;                   // output 1: (256,4,256,256)
  float* ax = (float*)d_ws;                       // 1 MB scratch

  (void)hipMemsetAsync(out, 0, OUT_ELEMS * sizeof(float), stream);
  adj_kernel<<<dim3(N_ * C_), dim3(256), 0, stream>>>(x, neighbor, adj, ax);
  gemm_kernel<<<dim3(256 / TM, O_ / TO, 16), dim3(256), 0, stream>>>(ax, x, W,
                                                                     out);
}

// Round 2
// 321.047 us; speedup vs baseline: 1.7469x; 1.7469x over previous
//
#include <hip/hip_runtime.h>
#include <math.h>

// Problem constants: N=256, C=4, F=256, NB=32, OC*OF=1024, K=2048
namespace {
constexpr int N_ = 256, C_ = 4, F_ = 256, NB_ = 32;
constexpr int O_ = 1024;
constexpr int OUT_ELEMS = N_ * O_;     // out (256,1024), then adj follows
constexpr int AX_ELEMS = N_ * C_ * F_; // 262144 floats = 1 MB
constexpr int SPLITK = 16;
typedef float f32x4 __attribute__((ext_vector_type(4)));  // native vec for nontemporal
}

// One block per (n,c). Algebra: fadj[a,b] = x[a]*s[b] + x[b]*s[a] (rank-1 sym,
// s = neighbor-sum), t = signsqrt(fadj), adj[a,b] = t[a,b]*inv[b],
// inv[b] = 1/(colsum_a |t[a,b]| + 1e-7), ax[b] = sum_a t[a,b]*(inv[a]*x[a]).
// KEY identity: sign(v)*sqrt(clip(|v|,1e-8)) == v * rsq(max(|v|,1e-8)).
__global__ __launch_bounds__(256) void adj_kernel(
    const float* __restrict__ x,         // (N,C,F)
    const float* __restrict__ neighbor,  // (N,NB,C,F)
    float* __restrict__ adj,             // (N,C,F,F)
    float* __restrict__ ax_out)          // (N,C,F) workspace
{
  __shared__ float4 xsw[F_];   // {x, s, w=inv*x, 0}
  __shared__ float red[4][F_];
  const int blk = blockIdx.x;
  const int n = blk >> 2, c = blk & 3;
  const int t = threadIdx.x;
  const int rs = t >> 6;         // row slice (wave id), rows [rs*64, rs*64+64)
  const int lane = t & 63;
  const int b0 = lane * 4;       // 4 owned columns

  // Stage x row and neighbor-sum row (coalesced).
  const int base = (n * C_ + c) * F_;
  {
    const float xv = x[base + t];
    const float* p = neighbor + ((size_t)(n * NB_) * C_ + c) * F_ + t;
    float s = 0.f;
    #pragma unroll
    for (int j = 0; j < NB_; ++j) s += p[(size_t)j * C_ * F_];
    xsw[t] = make_float4(xv, s, 0.f, 0.f);
  }
  __syncthreads();

  float xbv[4], sbv[4];
  #pragma unroll
  for (int j = 0; j < 4; ++j) {
    const float4 q = xsw[b0 + j];
    xbv[j] = q.x;
    sbv[j] = q.y;
  }

  // Phase 1: partial column sums of |t| over this thread's 64 rows.
  float cs[4] = {0.f, 0.f, 0.f, 0.f};
  const int a0r = rs * 64;
  #pragma unroll 4
  for (int a = a0r; a < a0r + 64; ++a) {
    const float2 xs = *(const float2*)&xsw[a];   // b64 broadcast
    const float xa = xs.x, sa = xs.y;
    #pragma unroll
    for (int j = 0; j < 4; ++j) {
      float v = fmaf(xa, sbv[j], xbv[j] * sa);
      float m = fmaxf(fabsf(v), 1e-8f);
      float rq = __builtin_amdgcn_rsqf(m);
      cs[j] = fmaf(fabsf(v), rq, cs[j]);         // |t| = |v|*rsq
    }
  }
  *(float4*)&red[rs][b0] = make_float4(cs[0], cs[1], cs[2], cs[3]);
  __syncthreads();

  float invv[4];
  {
    const float4 r0 = *(const float4*)&red[0][b0];
    const float4 r1 = *(const float4*)&red[1][b0];
    const float4 r2 = *(const float4*)&red[2][b0];
    const float4 r3 = *(const float4*)&red[3][b0];
    invv[0] = 1.f / (r0.x + r1.x + r2.x + r3.x + 1e-7f);
    invv[1] = 1.f / (r0.y + r1.y + r2.y + r3.y + 1e-7f);
    invv[2] = 1.f / (r0.z + r1.z + r2.z + r3.z + 1e-7f);
    invv[3] = 1.f / (r0.w + r1.w + r2.w + r3.w + 1e-7f);
  }
  if (rs == 0) {
    #pragma unroll
    for (int j = 0; j < 4; ++j) xsw[b0 + j].z = invv[j] * xbv[j];
  }
  __syncthreads();

  // Phase 2: recompute t, float4 nontemporal adj stores, ax accumulation.
  float axp[4] = {0.f, 0.f, 0.f, 0.f};
  float* arow = adj + (size_t)(n * C_ + c) * (F_ * F_);
  #pragma unroll 4
  for (int a = a0r; a < a0r + 64; ++a) {
    const float4 q = xsw[a];                     // single b128 broadcast
    const float xa = q.x, sa = q.y, wa = q.z;
    float o[4];
    #pragma unroll
    for (int j = 0; j < 4; ++j) {
      float v = fmaf(xa, sbv[j], xbv[j] * sa);
      float m = fmaxf(fabsf(v), 1e-8f);
      float rq = __builtin_amdgcn_rsqf(m);
      float tt = v * rq;                         // sign(v)*sqrt(|v|)
      o[j] = tt * invv[j];
      axp[j] = fmaf(tt, wa, axp[j]);
    }
    f32x4 ov = {o[0], o[1], o[2], o[3]};
    __builtin_nontemporal_store(ov, (f32x4*)&arow[(size_t)a * F_ + b0]);
  }
  *(float4*)&red[rs][b0] = make_float4(axp[0], axp[1], axp[2], axp[3]);
  __syncthreads();
  if (rs == 0) {
    const float4 r0 = *(const float4*)&red[0][b0];
    const float4 r1 = *(const float4*)&red[1][b0];
    const float4 r2 = *(const float4*)&red[2][b0];
    const float4 r3 = *(const float4*)&red[3][b0];
    const float4 axv = make_float4(r0.x + r1.x + r2.x + r3.x,
                                   r0.y + r1.y + r2.y + r3.y,
                                   r0.z + r1.z + r2.z + r3.z,
                                   r0.w + r1.w + r2.w + r3.w);
    *(float4*)&ax_out[base + b0] = axv;
  }
}

// out[m][o] = sum_k xcat[m][k] W[o][k], xcat = [ax | x] split at k=1024.
// 128x128 tile, 256 threads, 8x8 register micro-tile (64 fma per 4
// ds_read_b128), BK=32 staged transposed in LDS with skew p(c)=c+4*(c>>5).
// split-K=16, grid 2x8x16 = 256 blocks.
// USE_WS=true:  plain float4 stores of the partial tile into the workspace
//               (dst = partials base, slice blockIdx.z) -> NO atomics.
//               Round-1 post-mortem: 4.2M fp32 atomicAdds = 128 MB of RMW
//               sector writes, 285 us of atomic stall (VALUBusy 2.4%).
// USE_WS=false: legacy atomic fallback (only if ws_size too small).
namespace {
constexpr int TM = 128, TO = 128, BK = 32, PL = 144;  // padded/skewed row
__device__ __forceinline__ int swz(int c) { return c + ((c >> 5) << 2); }
}

template <bool USE_WS>
__global__ __launch_bounds__(256) void gemm_kernel(
    const float* __restrict__ ax,  // (256,1024)
    const float* __restrict__ x,   // (256,1024)
    const float* __restrict__ W,   // (1024,2048)
    float* __restrict__ dst)       // partials base (USE_WS) or out (atomic)
{
  __shared__ float As[BK * PL];  // [kk][m'] skewed
  __shared__ float Bs[BK * PL];  // [kk][o'] skewed
  const int tid = threadIdx.x;
  const int m0 = blockIdx.x * TM, o0 = blockIdx.y * TO;
  const int kbeg = blockIdx.z * 128;  // 128-aligned chunks never straddle halves
  const float* Ab = (kbeg < 1024) ? ax + kbeg : x + (kbeg - 1024);

  // staging coords: 2 threads per row, 16 k's each
  const int sr = tid >> 1;             // tile row (0..127)
  const int kq = (tid & 1) * 16;       // k offset within BK
  const int psr = swz(sr);
  // compute coords: 8x8 micro-tile
  const int mi = tid >> 4, oi = tid & 15;
  const int pa = swz(mi * 8), pb = swz(oi * 8);

  const float* Arow = Ab + (size_t)(m0 + sr) * 1024 + kq;
  const float* Brow = W + (size_t)(o0 + sr) * 2048 + kbeg + kq;

  float4 ra[4], rb[4];
  #pragma unroll
  for (int q = 0; q < 4; ++q) {
    ra[q] = *(const float4*)&Arow[q * 4];
    rb[q] = *(const float4*)&Brow[q * 4];
  }

  float acc[8][8] = {};

  for (int tt = 0; tt < 4; ++tt) {
    // staged regs -> LDS (transposed, skewed)
    #pragma unroll
    for (int q = 0; q < 4; ++q) {
      const float av[4] = {ra[q].x, ra[q].y, ra[q].z, ra[q].w};
      const float bv[4] = {rb[q].x, rb[q].y, rb[q].z, rb[q].w};
      #pragma unroll
      for (int e = 0; e < 4; ++e) {
        As[(kq + q * 4 + e) * PL + psr] = av[e];
        Bs[(kq + q * 4 + e) * PL + psr] = bv[e];
      }
    }
    __syncthreads();
    // register-prefetch next BK-tile; latency hides under 2048 fmas
    if (tt < 3) {
      #pragma unroll
      for (int q = 0; q < 4; ++q) {
        ra[q] = *(const float4*)&Arow[(tt + 1) * BK + q * 4];
        rb[q] = *(const float4*)&Brow[(tt + 1) * BK + q * 4];
      }
    }
    #pragma unroll 8
    for (int kk = 0; kk < BK; ++kk) {
      const float4 a0 = *(const float4*)&As[kk * PL + pa];
      const float4 a1 = *(const float4*)&As[kk * PL + pa + 4];
      const float4 b0 = *(const float4*)&Bs[kk * PL + pb];
      const float4 b1 = *(const float4*)&Bs[kk * PL + pb + 4];
      const float am[8] = {a0.x, a0.y, a0.z, a0.w, a1.x, a1.y, a1.z, a1.w};
      const float bm[8] = {b0.x, b0.y, b0.z, b0.w, b1.x, b1.y, b1.z, b1.w};
      #pragma unroll
      for (int i = 0; i < 8; ++i)
        #pragma unroll
        for (int j = 0; j < 8; ++j)
          acc[i][j] = fmaf(am[i], bm[j], acc[i][j]);
    }
    __syncthreads();  // reads done before next overwrite
  }

  if (USE_WS) {
    // coalesced partial-tile store (wave: oi 0..15 x 8 floats = 512B/row)
    float* p = dst + (size_t)blockIdx.z * OUT_ELEMS;
    #pragma unroll
    for (int i = 0; i < 8; ++i) {
      float* prow = &p[(size_t)(m0 + mi * 8 + i) * 1024 + o0 + oi * 8];
      *(float4*)&prow[0] = make_float4(acc[i][0], acc[i][1], acc[i][2], acc[i][3]);
      *(float4*)&prow[4] = make_float4(acc[i][4], acc[i][5], acc[i][6], acc[i][7]);
    }
  } else {
    #pragma unroll
    for (int i = 0; i < 8; ++i) {
      float* orow = &dst[(size_t)(m0 + mi * 8 + i) * 1024 + o0 + oi * 8];
      #pragma unroll
      for (int j = 0; j < 8; ++j) atomicAdd(&orow[j], acc[i][j]);
    }
  }
}

// out[i..i+3] = sum over SPLITK partial slices. 16 MB read (L2-warm) + 1 MB
// write. 256 blocks x 256 threads x 1 float4 each.
__global__ __launch_bounds__(256) void reduce_kernel(
    const float* __restrict__ parts, float* __restrict__ out) {
  const int i = (blockIdx.x * 256 + threadIdx.x) * 4;
  float4 s = make_float4(0.f, 0.f, 0.f, 0.f);
  #pragma unroll
  for (int z = 0; z < SPLITK; ++z) {
    const float4 v = *(const float4*)&parts[(size_t)z * OUT_ELEMS + i];
    s.x += v.x; s.y += v.y; s.z += v.z; s.w += v.w;
  }
  f32x4 sv = {s.x, s.y, s.z, s.w};
  __builtin_nontemporal_store(sv, (f32x4*)&out[i]);
}

extern "C" void kernel_launch(void* const* d_in, const int* in_sizes, int n_in,
                              void* d_out, int out_size, void* d_ws,
                              size_t ws_size, hipStream_t stream) {
  const float* x = (const float*)d_in[0];         // (256,4,256)
  const float* neighbor = (const float*)d_in[1];  // (256,32,4,256)
  const float* W = (const float*)d_in[2];         // (1024,2048)
  float* out = (float*)d_out;                     // output 0: (256,1024)
  float* adj = out + OUT_ELEMS;                   // output 1: (256,4,256,256)
  float* ax = (float*)d_ws;                       // 1 MB scratch

  adj_kernel<<<dim3(N_ * C_), dim3(256), 0, stream>>>(x, neighbor, adj, ax);

  const size_t need = (size_t)(AX_ELEMS + SPLITK * OUT_ELEMS) * sizeof(float);
  if (ws_size >= need) {
    float* parts = ax + AX_ELEMS;  // 16 MB of split-K partials
    gemm_kernel<true><<<dim3(256 / TM, O_ / TO, SPLITK), dim3(256), 0, stream>>>(
        ax, x, W, parts);
    reduce_kernel<<<dim3(OUT_ELEMS / (256 * 4)), dim3(256), 0, stream>>>(parts,
                                                                         out);
  } else {
    (void)hipMemsetAsync(out, 0, OUT_ELEMS * sizeof(float), stream);
    gemm_kernel<false><<<dim3(256 / TM, O_ / TO, SPLITK), dim3(256), 0, stream>>>(
        ax, x, W, out);
  }
}